// Round 1
// baseline (351.391 us; speedup 1.0000x reference)
//
#include <hip/hip_runtime.h>
#include <math.h>

#define NC    10
#define BATCH 256
#define IC    1152
#define LDIM  8
#define OC    16
#define BGRP  4
#define NBLK  (NC * (BATCH / BGRP))   // 640 blocks, %8==0 -> bijective XCD swizzle

__device__ __forceinline__ int xcd_swizzle(int bid, int nwg) {
    // cluster consecutive work ids on the same XCD (round-robin dispatch assumed)
    int cpx = nwg >> 3;
    return (bid & 7) * cpx + (bid >> 3);
}

// ---------------------------------------------------------------------------
// K2: s[n,b,o] = sum_i c[n,b,i] * priors[n,b,i,o], priors recomputed on the fly
//     priors[n,b,i,o] = sum_l x[b,i,l] * w[n,i,l,o]
// block = (n, group of 4 b's); 256 threads = 16 o-lanes x 16 i-groups
// ---------------------------------------------------------------------------
template<bool ITER0>
__global__ __launch_bounds__(256) void k2_s(
    const float* __restrict__ x, const float* __restrict__ w,
    const float* __restrict__ beta, const float* __restrict__ invd,
    float* __restrict__ s)
{
    __shared__ float c_lds[BGRP][IC];       // 18 KB
    __shared__ float red[BGRP][16][16];     // 4 KB

    int wg = xcd_swizzle(blockIdx.x, NBLK);
    int n  = wg >> 6;                // 64 b-groups per n
    int b0 = (wg & 63) * BGRP;
    int t  = threadIdx.x;

    // phase A: routing coefficients c into LDS
    for (int idx = t; idx < BGRP * IC; idx += 256) {
        int bb = idx / IC, i = idx - bb * IC;
        if (ITER0) {
            c_lds[bb][i] = 1.0f / 256.0f;   // softmax of zeros over B=256
        } else {
            float be = beta[((size_t)n * BATCH + b0 + bb) * IC + i];
            c_lds[bb][i] = __expf(be) * invd[n * IC + i];
        }
    }
    __syncthreads();

    int o = t & 15, g = t >> 4;
    float acc[BGRP] = {0.f, 0.f, 0.f, 0.f};
    for (int i = g; i < IC; i += 16) {      // 72 iterations
        const float* wp = w + (((size_t)n * IC + i) * LDIM) * OC + o;
        float w8[8];
#pragma unroll
        for (int l = 0; l < 8; ++l) w8[l] = wp[l * OC];   // 16 o-lanes -> 64B segs
#pragma unroll
        for (int bb = 0; bb < BGRP; ++bb) {
            const float4* xp = reinterpret_cast<const float4*>(
                x + ((size_t)(b0 + bb) * IC + i) * LDIM);
            float4 xa = xp[0], xb = xp[1];   // broadcast across 16 o-lanes
            float dot = xa.x * w8[0] + xa.y * w8[1] + xa.z * w8[2] + xa.w * w8[3]
                      + xb.x * w8[4] + xb.y * w8[5] + xb.z * w8[6] + xb.w * w8[7];
            acc[bb] += c_lds[bb][i] * dot;
        }
    }
#pragma unroll
    for (int bb = 0; bb < BGRP; ++bb) red[bb][g][o] = acc[bb];
    __syncthreads();
    if (t < BGRP * 16) {
        int bb = t >> 4, oo = t & 15;
        float sum = 0.f;
#pragma unroll
        for (int gg = 0; gg < 16; ++gg) sum += red[bb][gg][oo];
        s[((size_t)n * BATCH + b0 + bb) * OC + oo] = sum;
    }
}

// ---------------------------------------------------------------------------
// K3: global squash scale = sqrt(n2)/(1+n2), n2 = sum over ALL of s^2.
//     Single block -> deterministic fixed-order reduction. FINAL also writes v.
// ---------------------------------------------------------------------------
template<bool FINAL>
__global__ __launch_bounds__(1024) void k3_squash(
    const float* __restrict__ s, float* __restrict__ scale_p,
    float* __restrict__ out)
{
    __shared__ float red[16];
    __shared__ float sc_sh;
    int t = threadIdx.x;
    float acc = 0.f;
    for (int idx = t; idx < NC * BATCH * OC; idx += 1024) {
        float v = s[idx];
        acc += v * v;
    }
#pragma unroll
    for (int m = 32; m >= 1; m >>= 1) acc += __shfl_xor(acc, m, 64);
    if ((t & 63) == 0) red[t >> 6] = acc;
    __syncthreads();
    if (t == 0) {
        float n2 = 0.f;
#pragma unroll
        for (int k = 0; k < 16; ++k) n2 += red[k];
        float sc = sqrtf(n2) / (1.0f + n2);
        sc_sh = sc;
        *scale_p = sc;
    }
    __syncthreads();
    if (FINAL) {
        float sc = sc_sh;
        for (int idx = t; idx < NC * BATCH * OC; idx += 1024)
            out[idx] = s[idx] * sc;
    }
}

// ---------------------------------------------------------------------------
// K4: beta[n,b,i] (+)= sum_l x[b,i,l] * (sum_o w[n,i,l,o] * v[n,b,o]),
//     v = s*scale computed inline. 256 threads = 32 i-subs x 8 l-lanes.
// ---------------------------------------------------------------------------
template<bool ACCUM>
__global__ __launch_bounds__(256) void k4_beta(
    const float* __restrict__ x, const float* __restrict__ w,
    const float* __restrict__ s, const float* __restrict__ scale_p,
    float* __restrict__ beta)
{
    __shared__ float v_lds[BGRP][OC];
    int wg = xcd_swizzle(blockIdx.x, NBLK);
    int n  = wg >> 6;
    int b0 = (wg & 63) * BGRP;
    int t  = threadIdx.x;

    if (t < BGRP * OC) {
        int bb = t >> 4, o = t & 15;
        v_lds[bb][o] = s[((size_t)n * BATCH + b0 + bb) * OC + o] * (*scale_p);
    }
    __syncthreads();

    float v[BGRP][OC];
#pragma unroll
    for (int bb = 0; bb < BGRP; ++bb)
#pragma unroll
        for (int o = 0; o < OC; ++o) v[bb][o] = v_lds[bb][o];

    int l = t & 7, isub = t >> 3;           // 32 i-subs
    for (int i = isub; i < IC; i += 32) {   // 36 iterations
        const float4* wp = reinterpret_cast<const float4*>(
            w + (((size_t)n * IC + i) * LDIM + l) * OC);  // 8 l-lanes x 64B contiguous
        float4 w0 = wp[0], w1 = wp[1], w2 = wp[2], w3 = wp[3];
        float wf[16] = {w0.x, w0.y, w0.z, w0.w, w1.x, w1.y, w1.z, w1.w,
                        w2.x, w2.y, w2.z, w2.w, w3.x, w3.y, w3.z, w3.w};
        float inc[BGRP];
#pragma unroll
        for (int bb = 0; bb < BGRP; ++bb) {
            float wv = 0.f;
#pragma unroll
            for (int o = 0; o < OC; ++o) wv += wf[o] * v[bb][o];
            inc[bb] = x[((size_t)(b0 + bb) * IC + i) * LDIM + l] * wv;
        }
        // reduce over the 8 l-lanes (consecutive lanes -> xor masks 1,2,4)
#pragma unroll
        for (int m = 1; m < 8; m <<= 1) {
#pragma unroll
            for (int bb = 0; bb < BGRP; ++bb)
                inc[bb] += __shfl_xor(inc[bb], m, 64);
        }
        if (l == 0) {
#pragma unroll
            for (int bb = 0; bb < BGRP; ++bb) {
                size_t bi = ((size_t)n * BATCH + b0 + bb) * IC + i;
                beta[bi] = (ACCUM ? beta[bi] : 0.0f) + inc[bb];
            }
        }
    }
}

// ---------------------------------------------------------------------------
// K1: inv softmax denominator over batch: invd[n,i] = 1 / sum_b exp(beta[n,b,i])
// ---------------------------------------------------------------------------
__global__ __launch_bounds__(256) void k1_invd(const float* __restrict__ beta,
                                               float* __restrict__ invd)
{
    int idx = blockIdx.x * 256 + threadIdx.x;   // 11520 = 45 blocks exactly
    int n = idx / IC, i = idx - n * IC;
    const float* bp = beta + (size_t)n * BATCH * IC + i;
    float acc = 0.f;
    for (int b = 0; b < BATCH; ++b) acc += __expf(bp[(size_t)b * IC]);
    invd[idx] = 1.0f / acc;
}

// ---------------------------------------------------------------------------
extern "C" void kernel_launch(void* const* d_in, const int* in_sizes, int n_in,
                              void* d_out, int out_size, void* d_ws, size_t ws_size,
                              hipStream_t stream)
{
    const float* x = (const float*)d_in[0];   // [256,1152,8]
    const float* w = (const float*)d_in[1];   // [10,1152,8,16]
    float* out = (float*)d_out;               // [10,256,1,1,16] -> 40960 floats
    float* ws  = (float*)d_ws;

    float* beta  = ws;                                       // 2,949,120 floats
    float* invd  = beta + (size_t)NC * BATCH * IC;           //    11,520 floats
    float* s     = invd + (size_t)NC * IC;                   //    40,960 floats
    float* scale = s + (size_t)NC * BATCH * OC;              //         1 float
    // total ~12.0 MB of workspace

    dim3 blk(256), grid(NBLK);

    // iter 1: c = 1/256 (softmax of zeros over batch)
    k2_s<true><<<grid, blk, 0, stream>>>(x, w, beta, invd, s);
    k3_squash<false><<<1, 1024, 0, stream>>>(s, scale, out);
    k4_beta<false><<<grid, blk, 0, stream>>>(x, w, s, scale, beta);  // beta = p.v1
    // iter 2
    k1_invd<<<45, 256, 0, stream>>>(beta, invd);
    k2_s<false><<<grid, blk, 0, stream>>>(x, w, beta, invd, s);
    k3_squash<false><<<1, 1024, 0, stream>>>(s, scale, out);
    k4_beta<true><<<grid, blk, 0, stream>>>(x, w, s, scale, beta);   // beta += p.v2
    // iter 3
    k1_invd<<<45, 256, 0, stream>>>(beta, invd);
    k2_s<false><<<grid, blk, 0, stream>>>(x, w, beta, invd, s);
    k3_squash<true><<<1, 1024, 0, stream>>>(s, scale, out);          // out = v3
}